// Round 17
// baseline (592.553 us; speedup 1.0000x reference)
//
#include <hip/hip_runtime.h>
#include <hip/hip_bf16.h>

#define MM 8192
#define NN 11008
#define KK 4096
#define PKW 2048    // packed int32 words per output row

#define BM 256
#define BN 256
#define BKI 128                 // K per tile (i8)
#define NTI (KK / BKI)          // 32 K-tiles
#define NSTEP (NTI * 4)         // 128 ks-steps of K=32
#define NBM (MM / BM)           // 32
#define NBN (NN / BN)           // 43

typedef __attribute__((ext_vector_type(4)))  float f32x4;
typedef __attribute__((ext_vector_type(4)))  int   i32x4;
typedef __attribute__((ext_vector_type(16))) int   i32x16;
typedef __attribute__((ext_vector_type(8)))  short s16x8;
typedef __attribute__((ext_vector_type(4)))  short s16x4;

typedef __attribute__((address_space(3))) unsigned char        lds_u8;
typedef const __attribute__((address_space(1))) unsigned char  glb_u8;

static __device__ __forceinline__ unsigned short f2bf(float f) {
  union { float f; unsigned int u; } v; v.f = f;
  unsigned int u = v.u;
  u += 0x7fffu + ((u >> 16) & 1u);   // RNE
  return (unsigned short)(u >> 16);
}

// ---------------- workspace layout (PLANE-MAJOR per 256-row panel, 128-K block) ----
// ws: [panel][kb 0..31][plane 0..7][row 0..255][16B]; offset =
//   panel*1048576 + kb*32768 + p*4096 + r*16,  plane p = ks*2 + half.
// GEMM reads BOTH operands direct to registers: one fragment = 16B/lane at
//   base + kb*32768 + ks*8192 + half*4096 + row*16  -> two contiguous 512B
//   segments per instruction (perfectly coalesced global_load_dwordx4).

// ---------------- quantize x: per-row absmax -> i8, plane-major ----------------

__global__ __launch_bounds__(256) void int4lin_quant_x(
    const float* __restrict__ X, signed char* __restrict__ O, float* __restrict__ xs)
{
  const int row  = blockIdx.x;
  const int t    = threadIdx.x;
  const int lane = t & 63;
  const int wave = t >> 6;
  const float* xr = X + (size_t)row * KK;

  f32x4 v[4];
  float mx = 0.0f;
#pragma unroll
  for (int j = 0; j < 4; ++j) {
    v[j] = *(const f32x4*)(xr + t * 16 + j * 4);
#pragma unroll
    for (int e = 0; e < 4; ++e) mx = fmaxf(mx, fabsf(v[j][e]));
  }
#pragma unroll
  for (int off = 32; off; off >>= 1) mx = fmaxf(mx, __shfl_xor(mx, off));
  __shared__ float red[4];
  if (lane == 0) red[wave] = mx;
  __syncthreads();
  mx = fmaxf(fmaxf(red[0], red[1]), fmaxf(red[2], red[3]));
  mx = fmaxf(mx, 1e-30f);
  const float rs = 127.0f / mx;
  if (t == 0) xs[row] = mx / 127.0f;

  i32x4 o;
#pragma unroll
  for (int w = 0; w < 4; ++w) {
    int acc = 0;
#pragma unroll
    for (int e = 0; e < 4; ++e) {
      int q = __float2int_rn(v[w][e] * rs);
      q = max(-127, min(127, q));
      acc |= (q & 0xff) << (8 * e);
    }
    o[w] = acc;
  }
  signed char* dst = O + (size_t)(row >> 8) * 1048576
                       + (size_t)(t >> 3) * 32768 + (size_t)(t & 7) * 4096
                       + (size_t)(row & 255) * 16;
  *(i32x4*)dst = o;
}

// ---------------- quantize w: nibbles -> i8 q in [-7,8], plane-major ----------------

__global__ void int4lin_quant_w(const int* __restrict__ P, signed char* __restrict__ O) {
  const int ntot = NN * 256;       // 16-byte output groups
  int i = blockIdx.x * blockDim.x + threadIdx.x;
  const int stride = gridDim.x * blockDim.x;
  for (; i < ntot; i += stride) {
    const int row = i >> 8;
    const int gr  = i & 255;
    const int* src = P + (size_t)row * PKW + gr * 8;   // 8 words -> 16 i8
    i32x4 va = *(const i32x4*)src;
    i32x4 vb = *(const i32x4*)(src + 4);
    i32x4 o;
#pragma unroll
    for (int h = 0; h < 2; ++h) {
      i32x4 w = h ? vb : va;
#pragma unroll
      for (int p = 0; p < 2; ++p) {
        const int b0 = w[2 * p], b1 = w[2 * p + 1];
        const int q0 = (b0 & 15) - 7, q1 = ((b0 >> 4) & 15) - 7;
        const int q2 = (b1 & 15) - 7, q3 = ((b1 >> 4) & 15) - 7;
        o[h * 2 + p] = (q0 & 0xff) | ((q1 & 0xff) << 8) | ((q2 & 0xff) << 16) | ((q3 & 0xff) << 24);
      }
    }
    signed char* dst = O + (size_t)(row >> 8) * 1048576
                         + (size_t)(gr >> 3) * 32768 + (size_t)(gr & 7) * 4096
                         + (size_t)(row & 255) * 16;
    *(i32x4*)dst = o;
  }
}

// ---------------- 256x256 i8 GEMM: ALL-REGISTER, ZERO LDS, ZERO BARRIERS ----------
// R14-R16: tile wall ~6400 cyc robust to conflicts/barrier-count/prefetch/LDS
// volume -> the lockstep LDS-staged structure itself is the limit. A+B tiles
// are L2-resident (64KB unique/tile/CU, XCD swizzle) -> per common-mistake #7,
// drop LDS staging entirely. Each wave = independent stream of 128 steps
// {load 6 frags of step s+1 || 8 MFMAs of step s} (the AITER 1:1 interleave);
// compiler emits counted vmcnt (no barrier blocks it); 2 waves/SIMD drift ->
// VMEM || MFMA overlap. L1 serves the 4x intra-block A duplication.

__global__ __launch_bounds__(512, 2) void int4lin_gemm_i8(
    const signed char* __restrict__ Ai,   // plane-major panels
    const signed char* __restrict__ Bi,
    const float* __restrict__ xs,
    const float* __restrict__ scale,
    const float* __restrict__ bias,
    float* __restrict__ C)
{
  const int tid  = threadIdx.x;
  const int lane = tid & 63;
  const int wave = tid >> 6;
  const int wm = wave >> 2;          // 0..1
  const int wn = wave & 3;           // 0..3

  // T1: bijective XCD swizzle (1376 = 8*172); consecutive swz share bm
  const int bid = blockIdx.x;
  const int swz = (bid & 7) * 172 + (bid >> 3);
  const int bm = swz / NBN;
  const int bn = swz - bm * NBN;

  const int r5   = lane & 31;        // frag row/col within 32
  const int half = lane >> 5;        // k-half (16 i8) within instruction

  // per-wave fragment base pointers (include half-plane + row offsets)
  const signed char* pA = Ai + (size_t)bm * 1048576 + half * 4096
                             + (wm * 128 + r5) * 16;      // + step*8192 + mf*512
  const signed char* pB = Bi + (size_t)bn * 1048576 + half * 4096
                             + (wn * 64 + r5) * 16;       // + step*8192 + nf*512

  i32x16 acc[4][2] = {};             // [mf][nf]

  // step s (0..127): kb = s>>2, ks = s&3; byte offset = s*8192 exactly
  // (kb*32768 + ks*8192 == s*8192) -- single multiply, no decompose.
  auto loadf = [&](int s, i32x4 (&ar)[4], i32x4 (&br)[2]) {
    const size_t off = (size_t)s * 8192;
#pragma unroll
    for (int mf = 0; mf < 4; ++mf) ar[mf] = *(const i32x4*)(pA + off + mf * 512);
#pragma unroll
    for (int nf = 0; nf < 2; ++nf) br[nf] = *(const i32x4*)(pB + off + nf * 512);
  };

#define SWEEP(aR, bR)                                                                       \
  __builtin_amdgcn_s_setprio(1);                                                            \
  _Pragma("unroll")                                                                         \
  for (int mf = 0; mf < 4; ++mf) {                                                          \
    acc[mf][0] = __builtin_amdgcn_mfma_i32_32x32x32_i8(aR[mf], bR[0], acc[mf][0], 0, 0, 0); \
    acc[mf][1] = __builtin_amdgcn_mfma_i32_32x32x32_i8(aR[mf], bR[1], acc[mf][1], 0, 0, 0); \
  }                                                                                         \
  __builtin_amdgcn_s_setprio(0);

  i32x4 aE[4], bE[2], aO[4], bO[2];

  // prime step 0
  loadf(0, aE, bE);

#pragma unroll 1
  for (int s = 0; s < NSTEP; s += 2) {
    loadf(s + 1, aO, bO);                                 // s+1 <= 127 always
    SWEEP(aE, bE)                                         // consume step s
    loadf((s + 2 < NSTEP) ? s + 2 : NSTEP - 1, aE, bE);   // clamped tail reload
    SWEEP(aO, bO)                                         // consume step s+1
  }

  // epilogue: y = acc * xs[row] * scale[col] + bias[col], NON-TEMPORAL stores
  // C/D 32x32: col = lane&31, row = (reg&3) + 8*(reg>>2) + 4*half
  const size_t m0 = (size_t)bm * BM;
  const int colb = bn * BN + wn * 64 + r5;
#pragma unroll
  for (int mf = 0; mf < 4; ++mf) {
    const size_t rbase = m0 + wm * 128 + mf * 32 + 4 * half;
#pragma unroll
    for (int reg = 0; reg < 16; ++reg) {
      const size_t row = rbase + (reg & 3) + 8 * (reg >> 2);
      const float xsr = xs[row];
      float* cp = C + row * NN + colb;
#pragma unroll
      for (int nf = 0; nf < 2; ++nf) {
        const int col = colb + nf * 32;
        __builtin_nontemporal_store(
            (float)acc[mf][nf][reg] * xsr * scale[col] + bias[col], cp + nf * 32);
      }
    }
  }
#undef SWEEP
}

// ---------------- GEMM, inline-conversion bf16 fallback (no workspace needed) ----------------

__global__ __launch_bounds__(256) void int4lin_gemm_inline(
    const float* __restrict__ X,
    const int* __restrict__ P,
    const float* __restrict__ scale,
    const float* __restrict__ bias,
    float* __restrict__ C)
{
  __shared__ unsigned short As[128 * 64];
  __shared__ unsigned short Bs[128 * 64];

  const int tid  = threadIdx.x;
  const int lane = tid & 63;
  const int wave = tid >> 6;
  const int m0 = blockIdx.y * 128;
  const int n0 = blockIdx.x * 128;
  const int wr = (wave >> 1) * 64;
  const int wc = (wave & 1) * 64;

  f32x4 acc[4][4] = {};

  for (int kt = 0; kt < KK; kt += 64) {
#pragma unroll
    for (int i = 0; i < 8; ++i) {
      const int idx = i * 256 + tid;
      const int row = idx >> 4;
      const int c   = (idx & 15) << 2;
      f32x4 v = *(const f32x4*)(X + (size_t)(m0 + row) * KK + kt + c);
      s16x4 o;
      o[0] = (short)f2bf(v[0]); o[1] = (short)f2bf(v[1]);
      o[2] = (short)f2bf(v[2]); o[3] = (short)f2bf(v[3]);
      *(s16x4*)(As + row * 64 + (c ^ ((row & 7) << 3))) = o;
    }
#pragma unroll
    for (int i = 0; i < 4; ++i) {
      const int idx = i * 256 + tid;
      const int row = idx >> 3;
      const int c   = (idx & 7) << 3;
      i32x4 v = *(const i32x4*)(P + (size_t)(n0 + row) * PKW + ((kt + c) >> 1));
      s16x8 o;
#pragma unroll
      for (int j = 0; j < 4; ++j) {
        const int b = v[j];
        o[2 * j]     = (short)f2bf((float)((b & 15) - 7));
        o[2 * j + 1] = (short)f2bf((float)(((b >> 4) & 15) - 7));
      }
      *(s16x8*)(Bs + row * 64 + (c ^ ((row & 7) << 3))) = o;
    }
    __syncthreads();
#pragma unroll
    for (int kk = 0; kk < 2; ++kk) {
      const int rsel = lane & 15;
      const int ksel = ((((lane >> 4) << 3) + kk * 32)) ^ ((lane & 7) << 3);
      s16x8 af[4], bfr[4];
#pragma unroll
      for (int m = 0; m < 4; ++m)
        af[m] = *(const s16x8*)(As + (wr + m * 16 + rsel) * 64 + ksel);
#pragma unroll
      for (int n = 0; n < 4; ++n)
        bfr[n] = *(const s16x8*)(Bs + (wc + n * 16 + rsel) * 64 + ksel);
#pragma unroll
      for (int m = 0; m < 4; ++m)
#pragma unroll
        for (int n = 0; n < 4; ++n)
          acc[m][n] = __builtin_amdgcn_mfma_f32_16x16x32_bf16(af[m], bfr[n], acc[m][n], 0, 0, 0);
    }
    __syncthreads();
  }

  const int crow = wr + ((lane >> 4) << 2);
  const int ccol = wc + (lane & 15);
#pragma unroll
  for (int n = 0; n < 4; ++n) {
    const int gc = n0 + ccol + n * 16;
    const float sc = scale[gc];
    const float bi = bias[gc];
#pragma unroll
    for (int m = 0; m < 4; ++m) {
      float* cp = C + (size_t)(m0 + crow + m * 16) * NN + gc;
#pragma unroll
      for (int r = 0; r < 4; ++r)
        cp[(size_t)r * NN] = acc[m][n][r] * sc + bi;
    }
  }
}

// ---------------- launch ----------------

extern "C" void kernel_launch(void* const* d_in, const int* in_sizes, int n_in,
                              void* d_out, int out_size, void* d_ws, size_t ws_size,
                              hipStream_t stream) {
  const float* x      = (const float*)d_in[0];
  const int*   packed = (const int*)d_in[1];
  const float* scale  = (const float*)d_in[2];
  const float* bias   = (const float*)d_in[3];
  float* y = (float*)d_out;

  const size_t nXA = (size_t)MM * KK;                  // 32 MiB i8
  const size_t nWB = (size_t)NN * KK;                  // ~43 MiB i8
  const size_t nXS = (size_t)MM * sizeof(float);       // 32 KiB
  if (ws_size >= nXA + nWB + nXS) {
    signed char* xi = (signed char*)d_ws;
    signed char* wi = (signed char*)d_ws + nXA;
    float*       xsv = (float*)((char*)d_ws + nXA + nWB);
    int4lin_quant_x<<<MM, 256, 0, stream>>>(x, xi, xsv);
    int4lin_quant_w<<<2048, 256, 0, stream>>>(packed, wi);
    int4lin_gemm_i8<<<NBM * NBN, 512, 0, stream>>>(xi, wi, xsv, scale, bias, y);
    return;
  }
  dim3 grid(NN / 128, MM / 128);
  int4lin_gemm_inline<<<grid, 256, 0, stream>>>(x, packed, scale, bias, y);
}

// Round 18
// 524.439 us; speedup vs baseline: 1.1299x; 1.1299x over previous
//
#include <hip/hip_runtime.h>
#include <hip/hip_bf16.h>

#define MM 8192
#define NN 11008
#define KK 4096
#define PKW 2048    // packed int32 words per output row

#define BM 256
#define BN 256
#define BKI 128                 // K per tile (i8)
#define NTI (KK / BKI)          // 32 K-tiles
#define NBM (MM / BM)           // 32
#define NBN (NN / BN)           // 43
#define WBLK 2048               // fused-quant blocks assigned to W

typedef __attribute__((ext_vector_type(4)))  float f32x4;
typedef __attribute__((ext_vector_type(4)))  int   i32x4;
typedef __attribute__((ext_vector_type(16))) int   i32x16;
typedef __attribute__((ext_vector_type(8)))  short s16x8;
typedef __attribute__((ext_vector_type(4)))  short s16x4;

typedef __attribute__((address_space(3))) unsigned char        lds_u8;
typedef const __attribute__((address_space(1))) unsigned char  glb_u8;

static __device__ __forceinline__ unsigned short f2bf(float f) {
  union { float f; unsigned int u; } v; v.f = f;
  unsigned int u = v.u;
  u += 0x7fffu + ((u >> 16) & 1u);   // RNE
  return (unsigned short)(u >> 16);
}

// ---------------- workspace layout (PLANE-MAJOR per 256-row panel, 128-K block) ----
// ws: [panel][kb 0..31][plane 0..7][row 0..255][16B]; offset =
//   panel*1048576 + kb*32768 + p*4096 + r*16,  plane p = ks*2 + half.
// GEMM stages one (panel,kb) chunk = 32 KB CONTIGUOUS per operand per tile.

// ---------------- FUSED quantize: blocks [0,MM) do x-rows; [MM,MM+WBLK) do W ----

__global__ __launch_bounds__(256) void int4lin_quant_fused(
    const float* __restrict__ X, const int* __restrict__ P,
    signed char* __restrict__ OX, signed char* __restrict__ OW,
    float* __restrict__ xs)
{
  const int t = threadIdx.x;

  if (blockIdx.x < MM) {
    // ----- quant_x: per-row absmax -> i8, plane-major (identical to R15) -----
    const int row  = blockIdx.x;
    const int lane = t & 63;
    const int wave = t >> 6;
    const float* xr = X + (size_t)row * KK;

    f32x4 v[4];
    float mx = 0.0f;
#pragma unroll
    for (int j = 0; j < 4; ++j) {
      v[j] = *(const f32x4*)(xr + t * 16 + j * 4);
#pragma unroll
      for (int e = 0; e < 4; ++e) mx = fmaxf(mx, fabsf(v[j][e]));
    }
#pragma unroll
    for (int off = 32; off; off >>= 1) mx = fmaxf(mx, __shfl_xor(mx, off));
    __shared__ float red[4];
    if (lane == 0) red[wave] = mx;
    __syncthreads();
    mx = fmaxf(fmaxf(red[0], red[1]), fmaxf(red[2], red[3]));
    mx = fmaxf(mx, 1e-30f);
    const float rs = 127.0f / mx;
    if (t == 0) xs[row] = mx / 127.0f;

    i32x4 o;
#pragma unroll
    for (int w = 0; w < 4; ++w) {
      int acc = 0;
#pragma unroll
      for (int e = 0; e < 4; ++e) {
        int q = __float2int_rn(v[w][e] * rs);
        q = max(-127, min(127, q));
        acc |= (q & 0xff) << (8 * e);
      }
      o[w] = acc;
    }
    signed char* dst = OX + (size_t)(row >> 8) * 1048576
                          + (size_t)(t >> 3) * 32768 + (size_t)(t & 7) * 4096
                          + (size_t)(row & 255) * 16;
    *(i32x4*)dst = o;
  } else {
    // ----- quant_w: nibbles -> i8 q in [-7,8], plane-major (identical to R15) -----
    const int ntot = NN * 256;       // 16-byte output groups
    int i = (blockIdx.x - MM) * blockDim.x + t;
    const int stride = WBLK * blockDim.x;
    for (; i < ntot; i += stride) {
      const int row = i >> 8;
      const int gr  = i & 255;
      const int* src = P + (size_t)row * PKW + gr * 8;   // 8 words -> 16 i8
      i32x4 va = *(const i32x4*)src;
      i32x4 vb = *(const i32x4*)(src + 4);
      i32x4 o;
#pragma unroll
      for (int h = 0; h < 2; ++h) {
        i32x4 w = h ? vb : va;
#pragma unroll
        for (int p = 0; p < 2; ++p) {
          const int b0 = w[2 * p], b1 = w[2 * p + 1];
          const int q0 = (b0 & 15) - 7, q1 = ((b0 >> 4) & 15) - 7;
          const int q2 = (b1 & 15) - 7, q3 = ((b1 >> 4) & 15) - 7;
          o[h * 2 + p] = (q0 & 0xff) | ((q1 & 0xff) << 8) | ((q2 & 0xff) << 16) | ((q3 & 0xff) << 24);
        }
      }
      signed char* dst = OW + (size_t)(row >> 8) * 1048576
                            + (size_t)(gr >> 3) * 32768 + (size_t)(gr & 7) * 4096
                            + (size_t)(row & 255) * 16;
      *(i32x4*)dst = o;
    }
  }
}

// ---------------- 256x256x128 i8 GEMM: R15 CHAMPION (byte-identical) -------------
// Calibrated plateau: 6390 cyc/tile = MFMA 2292 + LDS 2048 + latency/convoy
// residual; robust to conflicts/barriers/prefetch/LDS-volume/occupancy
// (R9-R17). This is the best measured configuration: plane-major contiguous
// staging, 1 barrier/tile, intra-wave fragment read-ahead, NT C stores.

__global__ __launch_bounds__(512, 2) void int4lin_gemm_i8(
    const signed char* __restrict__ Ai,   // plane-major panels
    const signed char* __restrict__ Bi,
    const float* __restrict__ xs,
    const float* __restrict__ scale,
    const float* __restrict__ bias,
    float* __restrict__ C)
{
  __shared__ signed char As[2][32768];   // 2 x 32 KiB
  __shared__ signed char Bs[2][32768];   // 2 x 32 KiB -> 128 KiB

  const int tid  = threadIdx.x;
  const int lane = tid & 63;
  const int wave = tid >> 6;
  const int wm = wave >> 2;          // 0..1
  const int wn = wave & 3;           // 0..3

  // T1: bijective XCD swizzle (1376 = 8*172); consecutive swz share bm
  const int bid = blockIdx.x;
  const int swz = (bid & 7) * 172 + (bid >> 3);
  const int bm = swz / NBN;
  const int bn = swz - bm * NBN;

  const signed char* Abase = Ai + (size_t)bm * 1048576;
  const signed char* Bbase = Bi + (size_t)bn * 1048576;

  const int r5   = lane & 31;        // frag row/col within 32
  const int half = lane >> 5;        // k-half (16 i8) within instruction

  i32x16 acc[4][2] = {};             // [mf][nf]

  const int aoff0 = half * 4096 + (wm * 128 + r5) * 16;   // + ks*8192 + mf*512
  const int boff0 = half * 4096 + (wn * 64 + r5) * 16;    // + ks*8192 + nf*512

#define LDA(buf, mf, ks) (*(const i32x4*)(&As[buf][aoff0 + (ks) * 8192 + (mf) * 512]))
#define LDB(buf, nf, ks) (*(const i32x4*)(&Bs[buf][boff0 + (ks) * 8192 + (nf) * 512]))

  auto stage = [&](int buf, int kb) {
    const glb_u8* as = (const glb_u8*)(Abase + (size_t)kb * 32768 + tid * 16);
    const glb_u8* bs = (const glb_u8*)(Bbase + (size_t)kb * 32768 + tid * 16);
#pragma unroll
    for (int g = 0; g < 4; ++g)
      __builtin_amdgcn_global_load_lds(as + g * 8192,
          (lds_u8*)(&As[buf][g * 8192 + tid * 16]), 16, 0, 0);
#pragma unroll
    for (int g = 0; g < 4; ++g)
      __builtin_amdgcn_global_load_lds(bs + g * 8192,
          (lds_u8*)(&Bs[buf][g * 8192 + tid * 16]), 16, 0, 0);
  };

  // one MFMA sweep (8 distinct accumulators)
#define SWEEP(aR, bR)                                                                   \
  __builtin_amdgcn_s_setprio(1);                                                        \
  _Pragma("unroll")                                                                     \
  for (int mf = 0; mf < 4; ++mf) {                                                      \
    acc[mf][0] = __builtin_amdgcn_mfma_i32_32x32x32_i8(aR[mf], bR[0], acc[mf][0], 0, 0, 0); \
    acc[mf][1] = __builtin_amdgcn_mfma_i32_32x32x32_i8(aR[mf], bR[1], acc[mf][1], 0, 0, 0); \
  }                                                                                     \
  __builtin_amdgcn_s_setprio(0);

  // -------- prologue: stage tile0; full drain --------
  stage(0, 0);
  asm volatile("s_waitcnt vmcnt(0)\n\ts_barrier" ::: "memory");

#pragma unroll 1
  for (int t = 0; t < NTI; ++t) {
    const int buf = t & 1;

    // stage next tile into the other buffer (freed at boundary of t-1)
    if (t + 1 < NTI) stage(buf ^ 1, t + 1);

    i32x4 aA[4], bA[2], aB[4], bB[2];

    // prime ks0
#pragma unroll
    for (int mf = 0; mf < 4; ++mf) aA[mf] = LDA(buf, mf, 0);
#pragma unroll
    for (int nf = 0; nf < 2; ++nf) bA[nf] = LDB(buf, nf, 0);

    // step 0: read ks1 ahead; MFMA ks0
#pragma unroll
    for (int mf = 0; mf < 4; ++mf) aB[mf] = LDA(buf, mf, 1);
#pragma unroll
    for (int nf = 0; nf < 2; ++nf) bB[nf] = LDB(buf, nf, 1);
    SWEEP(aA, bA)

    // step 1: read ks2 ahead; MFMA ks1
#pragma unroll
    for (int mf = 0; mf < 4; ++mf) aA[mf] = LDA(buf, mf, 2);
#pragma unroll
    for (int nf = 0; nf < 2; ++nf) bA[nf] = LDB(buf, nf, 2);
    SWEEP(aB, bB)

    // step 2: read ks3 ahead; MFMA ks2
#pragma unroll
    for (int mf = 0; mf < 4; ++mf) aB[mf] = LDA(buf, mf, 3);
#pragma unroll
    for (int nf = 0; nf < 2; ++nf) bB[nf] = LDB(buf, nf, 3);
    SWEEP(aA, bA)

    // step 3: MFMA ks3
    SWEEP(aB, bB)

    // boundary: t+1's loads (issued a full tile ago) drained; safe switch
    if (t + 1 < NTI)
      asm volatile("s_waitcnt vmcnt(0)\n\ts_barrier" ::: "memory");
  }

  // epilogue: y = acc * xs[row] * scale[col] + bias[col], NON-TEMPORAL stores
  // C/D 32x32: col = lane&31, row = (reg&3) + 8*(reg>>2) + 4*half
  const size_t m0 = (size_t)bm * BM;
  const int colb = bn * BN + wn * 64 + r5;
#pragma unroll
  for (int mf = 0; mf < 4; ++mf) {
    const size_t rbase = m0 + wm * 128 + mf * 32 + 4 * half;
#pragma unroll
    for (int reg = 0; reg < 16; ++reg) {
      const size_t row = rbase + (reg & 3) + 8 * (reg >> 2);
      const float xsr = xs[row];
      float* cp = C + row * NN + colb;
#pragma unroll
      for (int nf = 0; nf < 2; ++nf) {
        const int col = colb + nf * 32;
        __builtin_nontemporal_store(
            (float)acc[mf][nf][reg] * xsr * scale[col] + bias[col], cp + nf * 32);
      }
    }
  }
#undef LDA
#undef LDB
#undef SWEEP
}

// ---------------- GEMM, inline-conversion bf16 fallback (no workspace needed) ----------------

__global__ __launch_bounds__(256) void int4lin_gemm_inline(
    const float* __restrict__ X,
    const int* __restrict__ P,
    const float* __restrict__ scale,
    const float* __restrict__ bias,
    float* __restrict__ C)
{
  __shared__ unsigned short As[128 * 64];
  __shared__ unsigned short Bs[128 * 64];

  const int tid  = threadIdx.x;
  const int lane = tid & 63;
  const int wave = tid >> 6;
  const int m0 = blockIdx.y * 128;
  const int n0 = blockIdx.x * 128;
  const int wr = (wave >> 1) * 64;
  const int wc = (wave & 1) * 64;

  f32x4 acc[4][4] = {};

  for (int kt = 0; kt < KK; kt += 64) {
#pragma unroll
    for (int i = 0; i < 8; ++i) {
      const int idx = i * 256 + tid;
      const int row = idx >> 4;
      const int c   = (idx & 15) << 2;
      f32x4 v = *(const f32x4*)(X + (size_t)(m0 + row) * KK + kt + c);
      s16x4 o;
      o[0] = (short)f2bf(v[0]); o[1] = (short)f2bf(v[1]);
      o[2] = (short)f2bf(v[2]); o[3] = (short)f2bf(v[3]);
      *(s16x4*)(As + row * 64 + (c ^ ((row & 7) << 3))) = o;
    }
#pragma unroll
    for (int i = 0; i < 4; ++i) {
      const int idx = i * 256 + tid;
      const int row = idx >> 3;
      const int c   = (idx & 7) << 3;
      i32x4 v = *(const i32x4*)(P + (size_t)(n0 + row) * PKW + ((kt + c) >> 1));
      s16x8 o;
#pragma unroll
      for (int j = 0; j < 4; ++j) {
        const int b = v[j];
        o[2 * j]     = (short)f2bf((float)((b & 15) - 7));
        o[2 * j + 1] = (short)f2bf((float)(((b >> 4) & 15) - 7));
      }
      *(s16x8*)(Bs + row * 64 + (c ^ ((row & 7) << 3))) = o;
    }
    __syncthreads();
#pragma unroll
    for (int kk = 0; kk < 2; ++kk) {
      const int rsel = lane & 15;
      const int ksel = ((((lane >> 4) << 3) + kk * 32)) ^ ((lane & 7) << 3);
      s16x8 af[4], bfr[4];
#pragma unroll
      for (int m = 0; m < 4; ++m)
        af[m] = *(const s16x8*)(As + (wr + m * 16 + rsel) * 64 + ksel);
#pragma unroll
      for (int n = 0; n < 4; ++n)
        bfr[n] = *(const s16x8*)(Bs + (wc + n * 16 + rsel) * 64 + ksel);
#pragma unroll
      for (int m = 0; m < 4; ++m)
#pragma unroll
        for (int n = 0; n < 4; ++n)
          acc[m][n] = __builtin_amdgcn_mfma_f32_16x16x32_bf16(af[m], bfr[n], acc[m][n], 0, 0, 0);
    }
    __syncthreads();
  }

  const int crow = wr + ((lane >> 4) << 2);
  const int ccol = wc + (lane & 15);
#pragma unroll
  for (int n = 0; n < 4; ++n) {
    const int gc = n0 + ccol + n * 16;
    const float sc = scale[gc];
    const float bi = bias[gc];
#pragma unroll
    for (int m = 0; m < 4; ++m) {
      float* cp = C + (size_t)(m0 + crow + m * 16) * NN + gc;
#pragma unroll
      for (int r = 0; r < 4; ++r)
        cp[(size_t)r * NN] = acc[m][n][r] * sc + bi;
    }
  }
}

// ---------------- launch ----------------

extern "C" void kernel_launch(void* const* d_in, const int* in_sizes, int n_in,
                              void* d_out, int out_size, void* d_ws, size_t ws_size,
                              hipStream_t stream) {
  const float* x      = (const float*)d_in[0];
  const int*   packed = (const int*)d_in[1];
  const float* scale  = (const float*)d_in[2];
  const float* bias   = (const float*)d_in[3];
  float* y = (float*)d_out;

  const size_t nXA = (size_t)MM * KK;                  // 32 MiB i8
  const size_t nWB = (size_t)NN * KK;                  // ~43 MiB i8
  const size_t nXS = (size_t)MM * sizeof(float);       // 32 KiB
  if (ws_size >= nXA + nWB + nXS) {
    signed char* xi = (signed char*)d_ws;
    signed char* wi = (signed char*)d_ws + nXA;
    float*       xsv = (float*)((char*)d_ws + nXA + nWB);
    int4lin_quant_fused<<<MM + WBLK, 256, 0, stream>>>(x, packed, xi, wi, xsv);
    int4lin_gemm_i8<<<NBM * NBN, 512, 0, stream>>>(xi, wi, xsv, scale, bias, y);
    return;
  }
  dim3 grid(NN / 128, MM / 128);
  int4lin_gemm_inline<<<grid, 256, 0, stream>>>(x, packed, scale, bias, y);
}